// Round 1
// baseline (11141.299 us; speedup 1.0000x reference)
//
#include <hip/hip_runtime.h>

#define THREADS 256

// Stage 1: out[rows[e]] += vals[e] * ego[cols[e]]  (COO scatter-add, fp32 atomics)
// 32 threads per edge, float4 per thread (32*4 = 128 dims).
__global__ void scatter_kernel(const float* __restrict__ ego,
                               const float* __restrict__ vals,
                               const int* __restrict__ rows,
                               const int* __restrict__ cols,
                               float* __restrict__ out,
                               int nEdges) {
    long long total  = (long long)nEdges * 32;
    long long stride = (long long)gridDim.x * blockDim.x;
    for (long long t = (long long)blockIdx.x * blockDim.x + threadIdx.x;
         t < total; t += stride) {
        int e = (int)(t >> 5);
        int g = (int)(t & 31);
        int r = rows[e];
        int c = cols[e];
        float v = vals[e];
        const float4* src = (const float4*)(ego + (long long)c * 128);
        float4 x = src[g];
        float* dst = out + (long long)r * 128 + (g << 2);
        atomicAdd(dst + 0, x.x * v);
        atomicAdd(dst + 1, x.y * v);
        atomicAdd(dst + 2, x.z * v);
        atomicAdd(dst + 3, x.w * v);
    }
}

// Stage 2: in-place per-row GEMM: out[r][j] = sum_k agg[r][k] * W[j][k]
// W staged fully in LDS (64 KB), read wave-uniform (broadcast).
// Each thread owns one row: 128 fp32 in VGPRs, 16 outputs per chunk.
__global__ __launch_bounds__(256) void rowgemm_kernel(float* __restrict__ out,
                                                      const float* __restrict__ W,
                                                      int nRows) {
    __shared__ float4 w4[128 * 32];   // W[j][k] as float4 over k: w4[j*32 + k4]
    const float4* Wg = (const float4*)W;
    for (int i = threadIdx.x; i < 128 * 32; i += THREADS) w4[i] = Wg[i];
    __syncthreads();

    int stride = gridDim.x * blockDim.x;
    for (int r = blockIdx.x * blockDim.x + threadIdx.x; r < nRows; r += stride) {
        float4* rowp = (float4*)(out + (long long)r * 128);
        float4 a[32];
#pragma unroll
        for (int i = 0; i < 32; ++i) a[i] = rowp[i];

#pragma unroll 1
        for (int jc = 0; jc < 8; ++jc) {
            float acc[16];
#pragma unroll
            for (int jj = 0; jj < 16; ++jj) acc[jj] = 0.f;
#pragma unroll
            for (int k4 = 0; k4 < 32; ++k4) {
                float4 av = a[k4];
#pragma unroll
                for (int jj = 0; jj < 16; ++jj) {
                    float4 wv = w4[(jc * 16 + jj) * 32 + k4];
                    acc[jj] += av.x * wv.x + av.y * wv.y + av.z * wv.z + av.w * wv.w;
                }
            }
            float4* op = rowp + jc * 4;
#pragma unroll
            for (int jj4 = 0; jj4 < 4; ++jj4)
                op[jj4] = make_float4(acc[jj4 * 4 + 0], acc[jj4 * 4 + 1],
                                      acc[jj4 * 4 + 2], acc[jj4 * 4 + 3]);
        }
    }
}

extern "C" void kernel_launch(void* const* d_in, const int* in_sizes, int n_in,
                              void* d_out, int out_size, void* d_ws, size_t ws_size,
                              hipStream_t stream) {
    const float* ego  = (const float*)d_in[0];
    const float* vals = (const float*)d_in[1];
    const float* W    = (const float*)d_in[2];
    const int*   rows = (const int*)d_in[3];
    const int*   cols = (const int*)d_in[4];

    int nEdges = in_sizes[1];
    int nRows  = in_sizes[0] / 128;
    float* out = (float*)d_out;

    // Zero the accumulator (d_out) — we accumulate into it with atomics.
    hipMemsetAsync(d_out, 0, (size_t)out_size * sizeof(float), stream);

    // Stage 1: scatter-add messages.
    {
        int blocks = 16384;  // grid-stride over 6.4M*32 = 204.8M work items
        scatter_kernel<<<blocks, THREADS, 0, stream>>>(ego, vals, rows, cols, out, nEdges);
    }

    // Stage 2: in-place row GEMM with W^T.
    {
        int blocks = (nRows + THREADS - 1) / THREADS;
        rowgemm_kernel<<<blocks, THREADS, 0, stream>>>(out, W, nRows);
    }
}

// Round 2
// 1506.479 us; speedup vs baseline: 7.3956x; 7.3956x over previous
//
#include <hip/hip_runtime.h>

#define THREADS 256
#define CHUNK 1024   // elements per scan chunk (THREADS * 4)

// ---------------- CSR build ----------------

__global__ void hist_kernel(const int* __restrict__ rows, int* __restrict__ counts,
                            int nEdges) {
    int stride = gridDim.x * blockDim.x;
    for (int e = blockIdx.x * blockDim.x + threadIdx.x; e < nEdges; e += stride)
        atomicAdd(&counts[rows[e]], 1);
}

__global__ void chunk_sum_kernel(const int* __restrict__ counts,
                                 int* __restrict__ chunkSums, int n) {
    __shared__ int s;
    if (threadIdx.x == 0) s = 0;
    __syncthreads();
    int i0 = blockIdx.x * CHUNK + threadIdx.x * 4;
    int local = 0;
#pragma unroll
    for (int k = 0; k < 4; ++k) {
        int i = i0 + k;
        if (i < n) local += counts[i];
    }
    atomicAdd(&s, local);
    __syncthreads();
    if (threadIdx.x == 0) chunkSums[blockIdx.x] = s;
}

// single block: exclusive scan of chunkSums -> chunkBase (any nChunks)
__global__ void scan_chunks_kernel(const int* __restrict__ chunkSums,
                                   int* __restrict__ chunkBase, int nChunks) {
    __shared__ int lds[THREADS];
    int per = (nChunks + THREADS - 1) / THREADS;
    int begin = threadIdx.x * per;
    int end = min(begin + per, nChunks);
    int sum = 0;
    for (int i = begin; i < end; ++i) sum += chunkSums[i];
    lds[threadIdx.x] = sum;
    __syncthreads();
    for (int off = 1; off < THREADS; off <<= 1) {
        int v = (threadIdx.x >= (unsigned)off) ? lds[threadIdx.x - off] : 0;
        __syncthreads();
        lds[threadIdx.x] += v;
        __syncthreads();
    }
    int base = (threadIdx.x == 0) ? 0 : lds[threadIdx.x - 1];
    for (int i = begin; i < end; ++i) {
        chunkBase[i] = base;
        base += chunkSums[i];
    }
}

__global__ void scan_within_kernel(const int* __restrict__ counts,
                                   const int* __restrict__ chunkBase,
                                   int* __restrict__ row_start, int n, int nEdges) {
    __shared__ int lds[THREADS];
    int i0 = blockIdx.x * CHUNK + threadIdx.x * 4;
    int c[4];
#pragma unroll
    for (int k = 0; k < 4; ++k) {
        int i = i0 + k;
        c[k] = (i < n) ? counts[i] : 0;
    }
    lds[threadIdx.x] = c[0] + c[1] + c[2] + c[3];
    __syncthreads();
    for (int off = 1; off < THREADS; off <<= 1) {
        int v = (threadIdx.x >= (unsigned)off) ? lds[threadIdx.x - off] : 0;
        __syncthreads();
        lds[threadIdx.x] += v;
        __syncthreads();
    }
    int tbase = chunkBase[blockIdx.x] + ((threadIdx.x == 0) ? 0 : lds[threadIdx.x - 1]);
#pragma unroll
    for (int k = 0; k < 4; ++k) {
        int i = i0 + k;
        if (i < n) row_start[i] = tbase;
        tbase += c[k];
    }
    if (blockIdx.x == 0 && threadIdx.x == 0) row_start[n] = nEdges;
}

__global__ void copy_int_kernel(const int* __restrict__ src, int* __restrict__ dst, int n) {
    int stride = gridDim.x * blockDim.x;
    for (int i = blockIdx.x * blockDim.x + threadIdx.x; i < n; i += stride)
        dst[i] = src[i];
}

__global__ void scatter_pairs_kernel(const int* __restrict__ rows,
                                     const int* __restrict__ cols,
                                     const float* __restrict__ vals,
                                     int* __restrict__ offsets,
                                     int2* __restrict__ pairs, int nEdges) {
    int stride = gridDim.x * blockDim.x;
    for (int e = blockIdx.x * blockDim.x + threadIdx.x; e < nEdges; e += stride) {
        int r = rows[e];
        int pos = atomicAdd(&offsets[r], 1);
        pairs[pos] = make_int2(cols[e], __float_as_int(vals[e]));
    }
}

// ---------------- atomic-free accumulate: one wave per destination row ----------------

__global__ __launch_bounds__(THREADS) void accum_kernel(const float* __restrict__ ego,
                                                        const int2* __restrict__ pairs,
                                                        const int* __restrict__ row_start,
                                                        float* __restrict__ out, int nRows) {
    int wid = blockIdx.x * (THREADS / 64) + (threadIdx.x >> 6);
    if (wid >= nRows) return;
    int lane = threadIdx.x & 63;
    int s = row_start[wid];
    int e = row_start[wid + 1];
    float2 acc = make_float2(0.f, 0.f);
    int i = s;
    for (; i + 1 < e; i += 2) {
        int2 p0 = pairs[i];
        int2 p1 = pairs[i + 1];
        float2 x0 = ((const float2*)(ego + (long long)p0.x * 128))[lane];
        float2 x1 = ((const float2*)(ego + (long long)p1.x * 128))[lane];
        float v0 = __int_as_float(p0.y);
        float v1 = __int_as_float(p1.y);
        acc.x += v0 * x0.x; acc.y += v0 * x0.y;
        acc.x += v1 * x1.x; acc.y += v1 * x1.y;
    }
    if (i < e) {
        int2 p = pairs[i];
        float2 x = ((const float2*)(ego + (long long)p.x * 128))[lane];
        float v = __int_as_float(p.y);
        acc.x += v * x.x; acc.y += v * x.y;
    }
    ((float2*)(out + (long long)wid * 128))[lane] = acc;
}

// ---------------- fallback: round-1 atomic scatter ----------------

__global__ void scatter_kernel(const float* __restrict__ ego,
                               const float* __restrict__ vals,
                               const int* __restrict__ rows,
                               const int* __restrict__ cols,
                               float* __restrict__ out, int nEdges) {
    long long total = (long long)nEdges * 32;
    long long stride = (long long)gridDim.x * blockDim.x;
    for (long long t = (long long)blockIdx.x * blockDim.x + threadIdx.x;
         t < total; t += stride) {
        int e = (int)(t >> 5);
        int g = (int)(t & 31);
        int r = rows[e];
        int c = cols[e];
        float v = vals[e];
        float4 x = ((const float4*)(ego + (long long)c * 128))[g];
        float* dst = out + (long long)r * 128 + (g << 2);
        atomicAdd(dst + 0, x.x * v);
        atomicAdd(dst + 1, x.y * v);
        atomicAdd(dst + 2, x.z * v);
        atomicAdd(dst + 3, x.w * v);
    }
}

// ---------------- stage 2: in-place row GEMM (out = agg @ W^T) ----------------

__global__ __launch_bounds__(THREADS) void rowgemm_kernel(float* __restrict__ out,
                                                          const float* __restrict__ W,
                                                          int nRows) {
    __shared__ float4 w4[128 * 32];   // W[j][k] as float4 over k
    const float4* Wg = (const float4*)W;
    for (int i = threadIdx.x; i < 128 * 32; i += THREADS) w4[i] = Wg[i];
    __syncthreads();

    int stride = gridDim.x * blockDim.x;
    for (int r = blockIdx.x * blockDim.x + threadIdx.x; r < nRows; r += stride) {
        float4* rowp = (float4*)(out + (long long)r * 128);
        float4 a[32];
#pragma unroll
        for (int i = 0; i < 32; ++i) a[i] = rowp[i];

#pragma unroll 1
        for (int jc = 0; jc < 8; ++jc) {
            float acc[16];
#pragma unroll
            for (int jj = 0; jj < 16; ++jj) acc[jj] = 0.f;
#pragma unroll
            for (int k4 = 0; k4 < 32; ++k4) {
                float4 av = a[k4];
#pragma unroll
                for (int jj = 0; jj < 16; ++jj) {
                    float4 wv = w4[(jc * 16 + jj) * 32 + k4];
                    acc[jj] += av.x * wv.x + av.y * wv.y + av.z * wv.z + av.w * wv.w;
                }
            }
            float4* op = rowp + jc * 4;
#pragma unroll
            for (int jj4 = 0; jj4 < 4; ++jj4)
                op[jj4] = make_float4(acc[jj4 * 4 + 0], acc[jj4 * 4 + 1],
                                      acc[jj4 * 4 + 2], acc[jj4 * 4 + 3]);
        }
    }
}

extern "C" void kernel_launch(void* const* d_in, const int* in_sizes, int n_in,
                              void* d_out, int out_size, void* d_ws, size_t ws_size,
                              hipStream_t stream) {
    const float* ego  = (const float*)d_in[0];
    const float* vals = (const float*)d_in[1];
    const float* W    = (const float*)d_in[2];
    const int*   rows = (const int*)d_in[3];
    const int*   cols = (const int*)d_in[4];

    int nEdges = in_sizes[1];
    int nRows  = in_sizes[0] / 128;
    float* out = (float*)d_out;

    int nChunks = (nRows + CHUNK - 1) / CHUNK;

    // workspace partition
    size_t off = 0;
    int* counts    = (int*)((char*)d_ws + off); off += (size_t)nRows * 4;
    int* row_start = (int*)((char*)d_ws + off); off += ((size_t)nRows + 1) * 4;
    int* offsets   = (int*)((char*)d_ws + off); off += (size_t)nRows * 4;
    int* chunkSums = (int*)((char*)d_ws + off); off += (size_t)nChunks * 4;
    int* chunkBase = (int*)((char*)d_ws + off); off += (size_t)nChunks * 4;
    off = (off + 15) & ~(size_t)15;
    int2* pairs    = (int2*)((char*)d_ws + off); off += (size_t)nEdges * 8;

    if (ws_size >= off) {
        // ---- CSR build + atomic-free accumulate ----
        hipMemsetAsync(counts, 0, (size_t)nRows * 4, stream);
        hist_kernel<<<4096, THREADS, 0, stream>>>(rows, counts, nEdges);
        chunk_sum_kernel<<<nChunks, THREADS, 0, stream>>>(counts, chunkSums, nRows);
        scan_chunks_kernel<<<1, THREADS, 0, stream>>>(chunkSums, chunkBase, nChunks);
        scan_within_kernel<<<nChunks, THREADS, 0, stream>>>(counts, chunkBase, row_start,
                                                            nRows, nEdges);
        copy_int_kernel<<<256, THREADS, 0, stream>>>(row_start, offsets, nRows);
        scatter_pairs_kernel<<<4096, THREADS, 0, stream>>>(rows, cols, vals, offsets,
                                                           pairs, nEdges);
        int accumBlocks = (nRows + (THREADS / 64) - 1) / (THREADS / 64);
        accum_kernel<<<accumBlocks, THREADS, 0, stream>>>(ego, pairs, row_start, out, nRows);
    } else {
        // ---- fallback: atomic scatter ----
        hipMemsetAsync(d_out, 0, (size_t)out_size * sizeof(float), stream);
        scatter_kernel<<<16384, THREADS, 0, stream>>>(ego, vals, rows, cols, out, nEdges);
    }

    // stage 2: in-place row GEMM with W^T
    rowgemm_kernel<<<(nRows + THREADS - 1) / THREADS, THREADS, 0, stream>>>(out, W, nRows);
}